// Round 8
// baseline (418.281 us; speedup 1.0000x reference)
//
#include <hip/hip_runtime.h>
#include <hip/hip_bf16.h>
#include <cstdint>
#include <cstddef>

// Shapes: B=2, S=512, C=25, H=768, 2H=1536, 3H=2304, 4H=3072
#define BB 2
#define SS 512
#define CC 25
#define HH 768
#define H2 1536
#define H3 2304
#define H4 3072
// chunked layout: [kc][row][8] bf16, kc = k/8
#define XC_STRIDE ((size_t)96 * 512 * 8)   // per-bc X slab, 96 chunks x 512 rows

typedef __attribute__((ext_vector_type(8))) short bf16x8;
typedef __attribute__((ext_vector_type(4))) float f32x4;

#define DEVINL static __device__ __forceinline__

DEVINL unsigned short f2bf(float f) {
  union { float f; unsigned u; } v; v.f = f;
  unsigned r = v.u + 0x7FFF + ((v.u >> 16) & 1);  // RNE
  return (unsigned short)(r >> 16);
}
DEVINL float bf2f(unsigned short b) {
  union { unsigned u; float f; } v; v.u = ((unsigned)b) << 16; return v.f;
}

DEVINL void async16(const void* g, void* l) {
  __builtin_amdgcn_global_load_lds(
      (const __attribute__((address_space(1))) void*)g,
      (__attribute__((address_space(3))) void*)l, 16, 0, 0);
}

// raw barrier (no implicit waitcnt drain) with compiler reorder fence
#define BAR() do { asm volatile("" ::: "memory"); \
                   __builtin_amdgcn_s_barrier();  \
                   asm volatile("" ::: "memory"); } while (0)
#define MFMA16(a, b, c) __builtin_amdgcn_mfma_f32_16x16x32_bf16(a, b, c, 0, 0, 0)

// ---------------- K1: all casts/chunking + out init (5316 blocks) ----------
__global__ void k_prep(const float* __restrict__ token,
                       const float* __restrict__ label,
                       const float* __restrict__ b2,
                       const float* __restrict__ Wt,
                       const float* __restrict__ Wl,
                       const float* __restrict__ W1,
                       unsigned short* __restrict__ TC,
                       unsigned short* __restrict__ LC,
                       float* __restrict__ out,
                       unsigned short* __restrict__ WtC,
                       unsigned short* __restrict__ WlC,
                       unsigned short* __restrict__ W1C) {
  __shared__ float tile[64][33];
  const int bid = blockIdx.x;
  const int tid = threadIdx.x;
  if (bid < 408) {
    const float* in;
    unsigned short* o;
    int R, RP, kt, rt;
    if (bid < 384) {
      in = token; o = TC; R = 1024; RP = 1024; kt = bid % 24; rt = bid / 24;
    } else {
      in = label; o = LC; R = 50; RP = 64; kt = bid - 384; rt = 0;
    }
    const int k0 = kt * 32, r0 = rt * 64;
    const int tx = tid & 31, ty = tid >> 5;
#pragma unroll
    for (int i = 0; i < 8; i++) {
      int r = r0 + ty + i * 8;
      tile[ty + i * 8][tx] = in[(size_t)min(r, R - 1) * HH + k0 + tx];
    }
    __syncthreads();
    const int rl = tid & 63, kcl = tid >> 6;
    bf16x8 ov;
#pragma unroll
    for (int j = 0; j < 8; j++) ov[j] = (short)f2bf(tile[rl][kcl * 8 + j]);
    *(bf16x8*)&o[((size_t)((k0 >> 3) + kcl) * RP + r0 + rl) * 8] = ov;
  } else if (bid < 708) {
    int i = (bid - 408) * 256 + tid;
    if (i < BB * SS * CC * 3) out[i] = b2[i % 3];
  } else {
    const int wb = bid - 708;
    const float* in;
    unsigned short* o;
    int N, bx, by;
    if (wb < 3456) {
      in = W1; o = W1C; N = H4; bx = wb % 48; by = wb / 48;
    } else if (wb < 4032) {
      int b = wb - 3456; in = Wt; o = WtC; N = H2; bx = b % 24; by = b / 24;
    } else {
      int b = wb - 4032; in = Wl; o = WlC; N = H2; bx = b % 24; by = b / 24;
    }
    const int f = bx * 64 + (tid & 63);
    const int hc = by * 4 + (tid >> 6);
    bf16x8 ov;
#pragma unroll
    for (int j = 0; j < 8; j++)
      ov[j] = (short)f2bf(in[(size_t)(hc * 8 + j) * N + f]);
    *(bf16x8*)&o[((size_t)hc * N + f) * 8] = ov;
  }
}

// ---------------- shared K-loop: 128x128 tile, K=768, chunked operands -----
DEVINL void mm_kloop(const unsigned short* __restrict__ Ab, int NRA, int MA,
                     int m0, const unsigned short* __restrict__ Bt, int NRB,
                     int n0, unsigned short* As, unsigned short* Bs,
                     f32x4 (&acc)[4][4]) {
  const int tid = threadIdx.x;
  const int lane = tid & 63;
  const int wave = tid >> 6;
  const int q = lane >> 4;
  const int li = lane & 15;
  const int wm = (wave >> 1) * 64;
  const int wn = (wave & 1) * 64;

  int sr[4], skc[4], sra[4];
#pragma unroll
  for (int j = 0; j < 4; j++) {
    int slot = j * 256 + tid;
    skc[j] = slot >> 7;
    sr[j] = slot & 127;
    sra[j] = min(m0 + sr[j], MA - 1);
  }
  auto stage = [&](int kciter) {
#pragma unroll
    for (int j = 0; j < 4; j++) {
      int slot = j * 256 + tid;
      async16(Ab + ((size_t)(kciter + skc[j]) * NRA + sra[j]) * 8,
              (char*)As + slot * 16);
      async16(Bt + ((size_t)(kciter + skc[j]) * NRB + n0 + sr[j]) * 8,
              (char*)Bs + slot * 16);
    }
  };

  stage(0);
  for (int it = 0; it < 12; it++) {
    __syncthreads();  // stage landed
#pragma unroll
    for (int ks = 0; ks < 2; ks++) {
      bf16x8 af[4], bb[4];
#pragma unroll
      for (int mi = 0; mi < 4; mi++)
        af[mi] = *(const bf16x8*)&As[((ks * 4 + q) * 128 + wm + mi * 16 + li) * 8];
#pragma unroll
      for (int ni = 0; ni < 4; ni++)
        bb[ni] = *(const bf16x8*)&Bs[((ks * 4 + q) * 128 + wn + ni * 16 + li) * 8];
#pragma unroll
      for (int mi = 0; mi < 4; mi++)
#pragma unroll
        for (int ni = 0; ni < 4; ni++)
          acc[mi][ni] = MFMA16(af[mi], bb[ni], acc[mi][ni]);
    }
    __syncthreads();  // all reads done
    if (it + 1 < 12) stage((it + 1) * 8);
  }
}

// ---------------- K2: G1+G2 fused (108 blocks) ----------------
__global__ __launch_bounds__(256, 4) void k_mm1(
    const unsigned short* __restrict__ TC, const unsigned short* __restrict__ LC,
    const unsigned short* __restrict__ WtC, const unsigned short* __restrict__ WlC,
    const float* __restrict__ bt, const float* __restrict__ bl,
    unsigned short* __restrict__ TP, unsigned short* __restrict__ LP) {
  __shared__ __align__(16) unsigned short As[8 * 128 * 8];
  __shared__ __align__(16) unsigned short Bs[8 * 128 * 8];
  const int bid = blockIdx.x;
  const int nt = bid % 12, my = bid / 12;
  const bool tok = my < 8;
  const unsigned short* A = tok ? TC : LC;
  const unsigned short* Bt = tok ? WtC : WlC;
  const float* bias = tok ? bt : bl;
  unsigned short* C = tok ? TP : LP;
  const int NRA = tok ? 1024 : 64, MA = tok ? 1024 : 50;
  const int m0 = tok ? my * 128 : 0;
  const int ldc = NRA;
  const int n0 = nt * 128;

  f32x4 acc[4][4];
#pragma unroll
  for (int i = 0; i < 4; i++)
#pragma unroll
    for (int j = 0; j < 4; j++) acc[i][j] = (f32x4){0.f, 0.f, 0.f, 0.f};
  mm_kloop(A, NRA, MA, m0, Bt, H2, n0, As, Bs, acc);

  const int lane = threadIdx.x & 63, wave = threadIdx.x >> 6;
  const int q = lane >> 4, li = lane & 15;
  const int wm = (wave >> 1) * 64, wn = (wave & 1) * 64;
#pragma unroll
  for (int mi = 0; mi < 4; mi++)
#pragma unroll
    for (int rr = 0; rr < 4; rr++) {
      int row = m0 + wm + mi * 16 + q * 4 + rr;
      if (row < MA) {
#pragma unroll
        for (int ni = 0; ni < 4; ni++) {
          int col = n0 + wn + ni * 16 + li;
          C[((size_t)(col >> 3) * ldc + row) * 8 + (col & 7)] =
              f2bf(acc[mi][ni][rr] + bias[col]);
        }
      }
    }
}

// ---------------- K3: G3+G4 (216 blocks) + make_x (9600 blocks) ----------------
__global__ __launch_bounds__(256, 4) void k_mm2(
    const unsigned short* __restrict__ TP, const unsigned short* __restrict__ LP,
    const unsigned short* __restrict__ W1C,
    float* __restrict__ base, float* __restrict__ al,
    unsigned short* __restrict__ XC) {
  __shared__ __align__(16) unsigned short As[8 * 128 * 8];
  __shared__ __align__(16) unsigned short Bs[8 * 128 * 8];
  const int bid = blockIdx.x;
  if (bid < 216) {
    const int nt = bid % 24, my = bid / 24;
    const bool tok = my < 8;
    const unsigned short* A = tok ? TP : LP;
    const unsigned short* Bt = tok ? W1C : W1C + (size_t)96 * H4 * 8;
    float* Cf = tok ? base : al;
    const int NRA = tok ? 1024 : 64, MA = tok ? 1024 : 50;
    const int m0 = tok ? my * 128 : 0;
    const int n0 = nt * 128;

    f32x4 acc[4][4];
#pragma unroll
    for (int i = 0; i < 4; i++)
#pragma unroll
      for (int j = 0; j < 4; j++) acc[i][j] = (f32x4){0.f, 0.f, 0.f, 0.f};
    mm_kloop(A, NRA, MA, m0, Bt, H4, n0, As, Bs, acc);

    const int lane = threadIdx.x & 63, wave = threadIdx.x >> 6;
    const int q = lane >> 4, li = lane & 15;
    const int wm = (wave >> 1) * 64, wn = (wave & 1) * 64;
#pragma unroll
    for (int mi = 0; mi < 4; mi++)
#pragma unroll
      for (int rr = 0; rr < 4; rr++) {
        int row = m0 + wm + mi * 16 + q * 4 + rr;
        if (row < MA) {
#pragma unroll
          for (int ni = 0; ni < 4; ni++) {
            int col = n0 + wn + ni * 16 + li;
            Cf[(size_t)row * H4 + col] = acc[mi][ni][rr];
          }
        }
      }
  } else {
    // make_x: XC[bc][hc][s][8] = tb_chunk(96+hc)[b*512+s] * lb_chunk(96+hc)[bc]
    const int i = bid - 216;           // 0..9599
    const int bc = i / 192;
    const int rem = i % 192;
    const int hc = rem >> 1;
    const int s = (rem & 1) * 256 + threadIdx.x;
    const int b = bc / CC;
    bf16x8 tv = *(const bf16x8*)&TP[((size_t)(96 + hc) * 1024 + b * 512 + s) * 8];
    bf16x8 lv = *(const bf16x8*)&LP[((size_t)(96 + hc) * 64 + bc) * 8];
    bf16x8 o;
#pragma unroll
    for (int j = 0; j < 8; j++)
      o[j] = (short)f2bf(bf2f((unsigned short)tv[j]) * bf2f((unsigned short)lv[j]));
    *(bf16x8*)&XC[(size_t)bc * XC_STRIDE + ((size_t)hc * 512 + s) * 8] = o;
  }
}

// ---------------- K4: G5 scorer (grid 24 x 200, LINEAR order) --------------
// R6 structure + ONE change: A-prefetch hoisted to the TOP of the iteration
// (ping-pong reg sets, full-iteration L2-latency cover; R6 covered only half
// an iteration). Linear block order restored (R7 showed the XCD swizzle
// doubled L2-miss traffic: each XCD naturally keeps only 3 of 24 B-slabs).
// B double-buffered 2x16 KB (32 KB -> 4 blocks/CU with launch_bounds(256,4)).
// FIFO ledger per iter: issue 4 B-stage then 8 A; vmcnt(8) at bottom retires
// exactly this iter's 4 B loads (full-iter cover); A(it+1) retires via the
// compiler's implicit wait at first MFMA use after the barrier.

#define STAGE_B4(KC0, DST) do {                                               \
    char* dst_ = (char*)(DST);                                                \
    _Pragma("unroll")                                                         \
    for (int j_ = 0; j_ < 4; j_++) {                                          \
      int slot_ = j_ * 256 + tid;                                             \
      async16(Bt + ((size_t)((KC0) + (slot_ >> 7)) * H4 + n0 + (slot_ & 127)) * 8, \
              dst_ + slot_ * 16);                                             \
    } } while (0)

// One K-step (K=64): stage B tile IT+1, prefetch A for IT+1 into NA*,
// compute tile IT from PREAD with CA*. Counted vmcnt(8) + raw barrier.
#define SC_BODY(IT, PREAD, PSTAGE, CA0, CA1, NA0, NA1) do {                   \
    if ((IT) + 1 < 12) STAGE_B4(((IT) + 1) * 8, (PSTAGE));                    \
    {                                                                         \
      const int cbn_ = ((IT) + 1 < 12) ? ((IT) + 1) * 8 : 88; /* clamp */     \
      _Pragma("unroll")                                                       \
      for (int mi_ = 0; mi_ < 4; mi_++)                                       \
        NA0[mi_] = *(const bf16x8*)(ap[mi_] + (size_t)(cbn_ + q) * 4096);     \
      _Pragma("unroll")                                                       \
      for (int mi_ = 0; mi_ < 4; mi_++)                                       \
        NA1[mi_] = *(const bf16x8*)(ap[mi_] + (size_t)(cbn_ + 4 + q) * 4096); \
    }                                                                         \
    {                                                                         \
      bf16x8 bb_[4];                                                          \
      _Pragma("unroll")                                                       \
      for (int ni_ = 0; ni_ < 4; ni_++)                                       \
        bb_[ni_] = *(const bf16x8*)&(PREAD)[((0 + q) * 128 + wn + ni_ * 16 + li) * 8]; \
      _Pragma("unroll")                                                       \
      for (int mi_ = 0; mi_ < 4; mi_++)                                       \
        _Pragma("unroll")                                                     \
        for (int ni_ = 0; ni_ < 4; ni_++)                                     \
          acc[mi_][ni_] = MFMA16(CA0[mi_], bb_[ni_], acc[mi_][ni_]);          \
      _Pragma("unroll")                                                       \
      for (int ni_ = 0; ni_ < 4; ni_++)                                       \
        bb_[ni_] = *(const bf16x8*)&(PREAD)[((4 + q) * 128 + wn + ni_ * 16 + li) * 8]; \
      _Pragma("unroll")                                                       \
      for (int mi_ = 0; mi_ < 4; mi_++)                                       \
        _Pragma("unroll")                                                     \
        for (int ni_ = 0; ni_ < 4; ni_++)                                     \
          acc[mi_][ni_] = MFMA16(CA1[mi_], bb_[ni_], acc[mi_][ni_]);          \
    }                                                                         \
    asm volatile("s_waitcnt vmcnt(8)" ::: "memory");                          \
    BAR();                                                                    \
  } while (0)

__global__ __launch_bounds__(256, 4) void k_scorer(
    const unsigned short* __restrict__ XC,   // per-bc slabs [96][512][8]
    const unsigned short* __restrict__ Bt,   // W1p chunked [96][3072][8]
    const float* __restrict__ base, const float* __restrict__ al,
    const float* __restrict__ b1, const float* __restrict__ W2,
    float* __restrict__ out) {
  __shared__ __align__(16) unsigned short Bs[2][8 * 128 * 8];  // 2 x 16 KB
  const int tid = threadIdx.x;
  const int lane = tid & 63;
  const int wave = tid >> 6;
  const int q = lane >> 4;
  const int li = lane & 15;
  const int wm = (wave >> 1) * 64;
  const int wn = (wave & 1) * 64;

  const int n0 = blockIdx.x * 128;
  const int bc = blockIdx.y >> 2;
  const int m0 = (blockIdx.y & 3) * 128;
  const unsigned short* Ab = XC + (size_t)bc * XC_STRIDE;

  // per-mi A fragment base pointers (row part constant; add chunk*4096 elems)
  const unsigned short* ap[4];
#pragma unroll
  for (int mi = 0; mi < 4; mi++)
    ap[mi] = Ab + (size_t)(m0 + wm + mi * 16 + li) * 8;

  f32x4 acc[4][4];
#pragma unroll
  for (int i = 0; i < 4; i++)
#pragma unroll
    for (int j = 0; j < 4; j++) acc[i][j] = (f32x4){0.f, 0.f, 0.f, 0.f};

  const unsigned short* c0 = &Bs[0][0];
  const unsigned short* c1 = &Bs[1][0];

  // prologue: B tile 0 staged; A for step 0 in regs. vmcnt(8) retires the 4
  // stage loads (oldest), leaves the 8 A-loads in flight.
  bf16x8 a0A[4], a0B[4], a1A[4], a1B[4];
  STAGE_B4(0, c0);
#pragma unroll
  for (int mi = 0; mi < 4; mi++)
    a0A[mi] = *(const bf16x8*)(ap[mi] + (size_t)(0 + q) * 4096);
#pragma unroll
  for (int mi = 0; mi < 4; mi++)
    a0B[mi] = *(const bf16x8*)(ap[mi] + (size_t)(4 + q) * 4096);
  asm volatile("s_waitcnt vmcnt(8)" ::: "memory");
  BAR();

#pragma unroll 1
  for (int tt = 0; tt < 6; tt++) {
    const int itE = 2 * tt;
    SC_BODY(itE,     c0, c1, a0A, a0B, a1A, a1B);   // read Bs0, stage Bs1
    SC_BODY(itE + 1, c1, c0, a1A, a1B, a0A, a0B);   // read Bs1, stage Bs0
  }

  // epilogue: E = acc + base + al + b1; relu; out += E @ W2 via MFMA.
  // All waves passed the final barrier; last tile read Bs[1]; scratch Bs[0].
  const int b = bc / CC, c = bc % CC;
  int fcol[4];
  float alb[4];
#pragma unroll
  for (int ni = 0; ni < 4; ni++) {
    int f = n0 + wn + ni * 16 + li;
    fcol[ni] = f;
    alb[ni] = al[(size_t)bc * H4 + f] + b1[f];
  }
  bf16x8 w2f[2];
#pragma unroll
  for (int ks = 0; ks < 2; ks++)
#pragma unroll
    for (int jj = 0; jj < 8; jj++) {
      int f = n0 + wn + ks * 32 + q * 8 + jj;
      float v = (li < 3) ? W2[(size_t)f * 3 + li] : 0.f;
      w2f[ks][jj] = (short)f2bf(v);
    }
  unsigned short* Ew = (unsigned short*)((char*)&Bs[0][0] + wave * 2304);

#pragma unroll
  for (int mi = 0; mi < 4; mi++) {
    float bs[4][4];
#pragma unroll
    for (int rr = 0; rr < 4; rr++) {
      int s_l = m0 + wm + mi * 16 + q * 4 + rr;
      const float* bp = base + (size_t)(b * SS + s_l) * H4;
#pragma unroll
      for (int ni = 0; ni < 4; ni++) bs[ni][rr] = bp[fcol[ni]];
    }
#pragma unroll
    for (int rr = 0; rr < 4; rr++)
#pragma unroll
      for (int ni = 0; ni < 4; ni++) {
        float v = acc[mi][ni][rr] + bs[ni][rr] + alb[ni];
        v = fmaxf(v, 0.f);
        Ew[(q * 4 + rr) * 72 + ni * 16 + li] = f2bf(v);
      }
    f32x4 oc = (f32x4){0.f, 0.f, 0.f, 0.f};
#pragma unroll
    for (int ks = 0; ks < 2; ks++) {
      bf16x8 ef = *(const bf16x8*)&Ew[li * 72 + ks * 32 + q * 8];
      oc = MFMA16(ef, w2f[ks], oc);
    }
#pragma unroll
    for (int rr = 0; rr < 4; rr++) {
      int s_l = m0 + wm + mi * 16 + q * 4 + rr;
      if (li < 3)
        atomicAdd(&out[((size_t)(b * SS + s_l) * CC + c) * 3 + li], oc[rr]);
    }
  }
}

// ---------------- host launch ----------------

extern "C" void kernel_launch(void* const* d_in, const int* in_sizes, int n_in,
                              void* d_out, int out_size, void* d_ws, size_t ws_size,
                              hipStream_t stream) {
  (void)in_sizes; (void)n_in; (void)ws_size; (void)out_size;
  const float* token = (const float*)d_in[0];
  const float* label = (const float*)d_in[1];
  const float* Wt    = (const float*)d_in[2];
  const float* bt    = (const float*)d_in[3];
  const float* Wl    = (const float*)d_in[4];
  const float* bl    = (const float*)d_in[5];
  const float* W1    = (const float*)d_in[6];
  const float* b1    = (const float*)d_in[7];
  const float* W2    = (const float*)d_in[8];
  const float* b2    = (const float*)d_in[9];
  float* out = (float*)d_out;

  char* p = (char*)d_ws;
  auto alloc = [&](size_t bytes) {
    char* r = p;
    p += (bytes + 255) & ~(size_t)255;
    return r;
  };
  unsigned short* TC  = (unsigned short*)alloc((size_t)96 * 1024 * 8 * 2);
  unsigned short* LC  = (unsigned short*)alloc((size_t)96 * 64 * 8 * 2);
  unsigned short* WtC = (unsigned short*)alloc((size_t)96 * 1536 * 8 * 2);
  unsigned short* WlC = (unsigned short*)alloc((size_t)96 * 1536 * 8 * 2);
  unsigned short* W1C = (unsigned short*)alloc((size_t)288 * 3072 * 8 * 2);
  unsigned short* TP  = (unsigned short*)alloc((size_t)192 * 1024 * 8 * 2);
  unsigned short* LP  = (unsigned short*)alloc((size_t)192 * 64 * 8 * 2);
  unsigned short* XC  = (unsigned short*)alloc((size_t)CC * BB * XC_STRIDE * 2);
  float* base = (float*)alloc((size_t)BB * SS * H4 * 4);
  float* al   = (float*)alloc((size_t)BB * CC * H4 * 4);

  // K1: all casts/chunking + out init
  k_prep<<<5316, 256, 0, stream>>>(token, label, b2, Wt, Wl, W1,
                                   TC, LC, out, WtC, WlC, W1C);
  // K2: G1+G2 fused projections
  k_mm1<<<108, 256, 0, stream>>>(TC, LC, WtC, WlC, bt, bl, TP, LP);
  // K3: G3+G4 GEMMs + make_x
  k_mm2<<<9816, 256, 0, stream>>>(TP, LP, W1C, base, al, XC);
  // K4: G5 scorer (A direct full-iter prefetch, B dbuf stage-at-top, linear)
  k_scorer<<<dim3(24, 200), 256, 0, stream>>>(
      XC, W1C + (size_t)192 * H4 * 8, base, al, b1, W2, out);
}

// Round 9
// 272.257 us; speedup vs baseline: 1.5363x; 1.5363x over previous
//
#include <hip/hip_runtime.h>
#include <hip/hip_bf16.h>
#include <cstdint>
#include <cstddef>

// Shapes: B=2, S=512, C=25, H=768, 2H=1536, 3H=2304, 4H=3072
#define BB 2
#define SS 512
#define CC 25
#define HH 768
#define H2 1536
#define H3 2304
#define H4 3072
// chunked layout: [kc][row][8] bf16, kc = k/8
#define XC_STRIDE ((size_t)96 * 512 * 8)   // per-bc X slab, 96 chunks x 512 rows

typedef __attribute__((ext_vector_type(8))) short bf16x8;
typedef __attribute__((ext_vector_type(4))) float f32x4;

#define DEVINL static __device__ __forceinline__

DEVINL unsigned short f2bf(float f) {
  union { float f; unsigned u; } v; v.f = f;
  unsigned r = v.u + 0x7FFF + ((v.u >> 16) & 1);  // RNE
  return (unsigned short)(r >> 16);
}
DEVINL float bf2f(unsigned short b) {
  union { unsigned u; float f; } v; v.u = ((unsigned)b) << 16; return v.f;
}

DEVINL void async16(const void* g, void* l) {
  __builtin_amdgcn_global_load_lds(
      (const __attribute__((address_space(1))) void*)g,
      (__attribute__((address_space(3))) void*)l, 16, 0, 0);
}

// raw barrier (no implicit waitcnt drain) with compiler reorder fence
#define BAR() do { asm volatile("" ::: "memory"); \
                   __builtin_amdgcn_s_barrier();  \
                   asm volatile("" ::: "memory"); } while (0)
#define MFMA16(a, b, c) __builtin_amdgcn_mfma_f32_16x16x32_bf16(a, b, c, 0, 0, 0)

// ---------------- K1: small casts + out init (1860 blocks) ----------
// bid [0,384): token [1024][768] -> TC [96][1024][8]
// bid [384,408): label [50][768] -> LC [96][64][8]
// bid [408,708): out init = b2 broadcast
// bid [708,1284): Wt [768][1536] -> WtC [96][1536][8]
// bid [1284,1860): Wl -> WlC
// (W1 cast moved into k_mm1's launch — fills the 148 idle CUs there.)
__global__ void k_prep(const float* __restrict__ token,
                       const float* __restrict__ label,
                       const float* __restrict__ b2,
                       const float* __restrict__ Wt,
                       const float* __restrict__ Wl,
                       unsigned short* __restrict__ TC,
                       unsigned short* __restrict__ LC,
                       float* __restrict__ out,
                       unsigned short* __restrict__ WtC,
                       unsigned short* __restrict__ WlC) {
  __shared__ float tile[64][33];
  const int bid = blockIdx.x;
  const int tid = threadIdx.x;
  if (bid < 408) {
    const float* in;
    unsigned short* o;
    int R, RP, kt, rt;
    if (bid < 384) {
      in = token; o = TC; R = 1024; RP = 1024; kt = bid % 24; rt = bid / 24;
    } else {
      in = label; o = LC; R = 50; RP = 64; kt = bid - 384; rt = 0;
    }
    const int k0 = kt * 32, r0 = rt * 64;
    const int tx = tid & 31, ty = tid >> 5;
#pragma unroll
    for (int i = 0; i < 8; i++) {
      int r = r0 + ty + i * 8;
      tile[ty + i * 8][tx] = in[(size_t)min(r, R - 1) * HH + k0 + tx];
    }
    __syncthreads();
    const int rl = tid & 63, kcl = tid >> 6;
    bf16x8 ov;
#pragma unroll
    for (int j = 0; j < 8; j++) ov[j] = (short)f2bf(tile[rl][kcl * 8 + j]);
    *(bf16x8*)&o[((size_t)((k0 >> 3) + kcl) * RP + r0 + rl) * 8] = ov;
  } else if (bid < 708) {
    int i = (bid - 408) * 256 + tid;
    if (i < BB * SS * CC * 3) out[i] = b2[i % 3];
  } else {
    const int wb = bid - 708;
    const float* in;
    unsigned short* o;
    int bx, by;
    if (wb < 576) {
      in = Wt; o = WtC; bx = wb % 24; by = wb / 24;
    } else {
      int b = wb - 576; in = Wl; o = WlC; bx = b % 24; by = b / 24;
    }
    const int f = bx * 64 + (tid & 63);
    const int hc = by * 4 + (tid >> 6);
    bf16x8 ov;
#pragma unroll
    for (int j = 0; j < 8; j++)
      ov[j] = (short)f2bf(in[(size_t)(hc * 8 + j) * H2 + f]);
    *(bf16x8*)&o[((size_t)hc * H2 + f) * 8] = ov;
  }
}

// ---------------- shared K-loop: 128x128 tile, K=768, chunked operands -----
DEVINL void mm_kloop(const unsigned short* __restrict__ Ab, int NRA, int MA,
                     int m0, const unsigned short* __restrict__ Bt, int NRB,
                     int n0, unsigned short* As, unsigned short* Bs,
                     f32x4 (&acc)[4][4]) {
  const int tid = threadIdx.x;
  const int lane = tid & 63;
  const int wave = tid >> 6;
  const int q = lane >> 4;
  const int li = lane & 15;
  const int wm = (wave >> 1) * 64;
  const int wn = (wave & 1) * 64;

  int sr[4], skc[4], sra[4];
#pragma unroll
  for (int j = 0; j < 4; j++) {
    int slot = j * 256 + tid;
    skc[j] = slot >> 7;
    sr[j] = slot & 127;
    sra[j] = min(m0 + sr[j], MA - 1);
  }
  auto stage = [&](int kciter) {
#pragma unroll
    for (int j = 0; j < 4; j++) {
      int slot = j * 256 + tid;
      async16(Ab + ((size_t)(kciter + skc[j]) * NRA + sra[j]) * 8,
              (char*)As + slot * 16);
      async16(Bt + ((size_t)(kciter + skc[j]) * NRB + n0 + sr[j]) * 8,
              (char*)Bs + slot * 16);
    }
  };

  stage(0);
  for (int it = 0; it < 12; it++) {
    __syncthreads();  // stage landed
#pragma unroll
    for (int ks = 0; ks < 2; ks++) {
      bf16x8 af[4], bb[4];
#pragma unroll
      for (int mi = 0; mi < 4; mi++)
        af[mi] = *(const bf16x8*)&As[((ks * 4 + q) * 128 + wm + mi * 16 + li) * 8];
#pragma unroll
      for (int ni = 0; ni < 4; ni++)
        bb[ni] = *(const bf16x8*)&Bs[((ks * 4 + q) * 128 + wn + ni * 16 + li) * 8];
#pragma unroll
      for (int mi = 0; mi < 4; mi++)
#pragma unroll
        for (int ni = 0; ni < 4; ni++)
          acc[mi][ni] = MFMA16(af[mi], bb[ni], acc[mi][ni]);
    }
    __syncthreads();  // all reads done
    if (it + 1 < 12) stage((it + 1) * 8);
  }
}

// ---------------- K2: G1+G2 fused (108 blocks) + W1 cast (3456 blocks) -----
// The W1C cast rides in this launch: k_mm1's GEMM uses only 108 of 256 CUs,
// so the cast fills the idle CUs. W1C is first consumed by k_mm2 (next
// launch) — stream order guarantees completion.
__global__ __launch_bounds__(256, 4) void k_mm1(
    const unsigned short* __restrict__ TC, const unsigned short* __restrict__ LC,
    const unsigned short* __restrict__ WtC, const unsigned short* __restrict__ WlC,
    const float* __restrict__ bt, const float* __restrict__ bl,
    const float* __restrict__ W1,
    unsigned short* __restrict__ TP, unsigned short* __restrict__ LP,
    unsigned short* __restrict__ W1C) {
  __shared__ __align__(16) unsigned short As[8 * 128 * 8];
  __shared__ __align__(16) unsigned short Bs[8 * 128 * 8];
  const int bid = blockIdx.x;
  const int tid = threadIdx.x;
  if (bid >= 108) {
    // W1 [2304][3072] -> W1C [288][3072][8]
    const int wb = bid - 108;
    const int bx = wb % 48, by = wb / 48;
    const int f = bx * 64 + (tid & 63);
    const int hc = by * 4 + (tid >> 6);
    bf16x8 ov;
#pragma unroll
    for (int j = 0; j < 8; j++)
      ov[j] = (short)f2bf(W1[(size_t)(hc * 8 + j) * H4 + f]);
    *(bf16x8*)&W1C[((size_t)hc * H4 + f) * 8] = ov;
    return;
  }
  const int nt = bid % 12, my = bid / 12;
  const bool tok = my < 8;
  const unsigned short* A = tok ? TC : LC;
  const unsigned short* Bt = tok ? WtC : WlC;
  const float* bias = tok ? bt : bl;
  unsigned short* C = tok ? TP : LP;
  const int NRA = tok ? 1024 : 64, MA = tok ? 1024 : 50;
  const int m0 = tok ? my * 128 : 0;
  const int ldc = NRA;
  const int n0 = nt * 128;

  f32x4 acc[4][4];
#pragma unroll
  for (int i = 0; i < 4; i++)
#pragma unroll
    for (int j = 0; j < 4; j++) acc[i][j] = (f32x4){0.f, 0.f, 0.f, 0.f};
  mm_kloop(A, NRA, MA, m0, Bt, H2, n0, As, Bs, acc);

  const int lane = threadIdx.x & 63, wave = threadIdx.x >> 6;
  const int q = lane >> 4, li = lane & 15;
  const int wm = (wave >> 1) * 64, wn = (wave & 1) * 64;
#pragma unroll
  for (int mi = 0; mi < 4; mi++)
#pragma unroll
    for (int rr = 0; rr < 4; rr++) {
      int row = m0 + wm + mi * 16 + q * 4 + rr;
      if (row < MA) {
#pragma unroll
        for (int ni = 0; ni < 4; ni++) {
          int col = n0 + wn + ni * 16 + li;
          C[((size_t)(col >> 3) * ldc + row) * 8 + (col & 7)] =
              f2bf(acc[mi][ni][rr] + bias[col]);
        }
      }
    }
}

// ---------------- K3: G3+G4 (216 blocks) + make_x (9600 blocks) ----------------
__global__ __launch_bounds__(256, 4) void k_mm2(
    const unsigned short* __restrict__ TP, const unsigned short* __restrict__ LP,
    const unsigned short* __restrict__ W1C,
    float* __restrict__ base, float* __restrict__ al,
    unsigned short* __restrict__ XC) {
  __shared__ __align__(16) unsigned short As[8 * 128 * 8];
  __shared__ __align__(16) unsigned short Bs[8 * 128 * 8];
  const int bid = blockIdx.x;
  if (bid < 216) {
    const int nt = bid % 24, my = bid / 24;
    const bool tok = my < 8;
    const unsigned short* A = tok ? TP : LP;
    const unsigned short* Bt = tok ? W1C : W1C + (size_t)96 * H4 * 8;
    float* Cf = tok ? base : al;
    const int NRA = tok ? 1024 : 64, MA = tok ? 1024 : 50;
    const int m0 = tok ? my * 128 : 0;
    const int n0 = nt * 128;

    f32x4 acc[4][4];
#pragma unroll
    for (int i = 0; i < 4; i++)
#pragma unroll
      for (int j = 0; j < 4; j++) acc[i][j] = (f32x4){0.f, 0.f, 0.f, 0.f};
    mm_kloop(A, NRA, MA, m0, Bt, H4, n0, As, Bs, acc);

    const int lane = threadIdx.x & 63, wave = threadIdx.x >> 6;
    const int q = lane >> 4, li = lane & 15;
    const int wm = (wave >> 1) * 64, wn = (wave & 1) * 64;
#pragma unroll
    for (int mi = 0; mi < 4; mi++)
#pragma unroll
      for (int rr = 0; rr < 4; rr++) {
        int row = m0 + wm + mi * 16 + q * 4 + rr;
        if (row < MA) {
#pragma unroll
          for (int ni = 0; ni < 4; ni++) {
            int col = n0 + wn + ni * 16 + li;
            Cf[(size_t)row * H4 + col] = acc[mi][ni][rr];
          }
        }
      }
  } else {
    // make_x: XC[bc][hc][s][8] = tb_chunk(96+hc)[b*512+s] * lb_chunk(96+hc)[bc]
    const int i = bid - 216;           // 0..9599
    const int bc = i / 192;
    const int rem = i % 192;
    const int hc = rem >> 1;
    const int s = (rem & 1) * 256 + threadIdx.x;
    const int b = bc / CC;
    bf16x8 tv = *(const bf16x8*)&TP[((size_t)(96 + hc) * 1024 + b * 512 + s) * 8];
    bf16x8 lv = *(const bf16x8*)&LP[((size_t)(96 + hc) * 64 + bc) * 8];
    bf16x8 o;
#pragma unroll
    for (int j = 0; j < 8; j++)
      o[j] = (short)f2bf(bf2f((unsigned short)tv[j]) * bf2f((unsigned short)lv[j]));
    *(bf16x8*)&XC[(size_t)bc * XC_STRIDE + ((size_t)hc * 512 + s) * 8] = o;
  }
}

// ---------------- K4: G5 scorer (grid 24 x 200) — R6 verbatim --------------
// A direct global->register ping-pong (one K-step ahead), B double-buffered
// LDS with STAGE at the TOP of each iteration, one barrier per iteration
// preceded by counted s_waitcnt vmcnt(8) — retires the 4 stage loads, keeps
// the 8 A prefetches in flight across the barrier. Best measured: 153.6 µs,
// MfmaUtil 35.9%. VMEM-byte-bound at this tile size (R7/R8 falsified the
// deeper-pipeline and swizzle levers; full-iter A-cover doesn't fit regs).

#define STAGE_B4(KC0, BI) do {                                                \
    char* dst_ = (char*)&Bs[BI][0];                                           \
    _Pragma("unroll")                                                         \
    for (int j_ = 0; j_ < 4; j_++) {                                          \
      int slot_ = j_ * 256 + tid;                                             \
      async16(Bt + ((size_t)((KC0) + (slot_ >> 7)) * H4 + n0 + (slot_ & 127)) * 8, \
              dst_ + slot_ * 16);                                             \
    } } while (0)

__global__ __launch_bounds__(256, 4) void k_scorer(
    const unsigned short* __restrict__ XC,   // per-bc slabs [96][512][8]
    const unsigned short* __restrict__ Bt,   // W1p chunked [96][3072][8]
    const float* __restrict__ base, const float* __restrict__ al,
    const float* __restrict__ b1, const float* __restrict__ W2,
    float* __restrict__ out) {
  __shared__ __align__(16) unsigned short Bs[2][8 * 128 * 8];  // 2 x 16 KB
  const int tid = threadIdx.x;
  const int lane = tid & 63;
  const int wave = tid >> 6;
  const int q = lane >> 4;
  const int li = lane & 15;
  const int wm = (wave >> 1) * 64;
  const int wn = (wave & 1) * 64;

  const int n0 = blockIdx.x * 128;
  const int bc = blockIdx.y >> 2;
  const int m0 = (blockIdx.y & 3) * 128;
  const unsigned short* Ab = XC + (size_t)bc * XC_STRIDE;

  // per-mi A fragment base pointers (row part constant; add chunk*4096 elems)
  const unsigned short* ap[4];
#pragma unroll
  for (int mi = 0; mi < 4; mi++)
    ap[mi] = Ab + (size_t)(m0 + wm + mi * 16 + li) * 8;

  f32x4 acc[4][4];
#pragma unroll
  for (int i = 0; i < 4; i++)
#pragma unroll
    for (int j = 0; j < 4; j++) acc[i][j] = (f32x4){0.f, 0.f, 0.f, 0.f};

  // prologue: B tile 0 staged first, then A fragments for steps 0,1.
  // vmcnt(8) retires the 4 stage loads (oldest); af loads stay in flight.
  STAGE_B4(0, 0);
  bf16x8 af0[4], af1[4];
#pragma unroll
  for (int mi = 0; mi < 4; mi++)
    af0[mi] = *(const bf16x8*)(ap[mi] + (size_t)(0 + q) * 4096);
#pragma unroll
  for (int mi = 0; mi < 4; mi++)
    af1[mi] = *(const bf16x8*)(ap[mi] + (size_t)(4 + q) * 4096);
  asm volatile("s_waitcnt vmcnt(8)" ::: "memory");
  BAR();

#pragma unroll 1
  for (int it = 0; it < 12; it++) {
    // issue next tile's staging FIRST — full compute phase covers latency.
    // Writes go to Bs[(it+1)&1]; current reads are from Bs[it&1] (disjoint).
    if (it < 11) STAGE_B4((it + 1) * 8, (it + 1) & 1);
    const unsigned short* Bd = &Bs[it & 1][0];
    bf16x8 bb[4];
    // ---- ks = 0: consume af0, prefetch af0 <- step 2*(it+1)
#pragma unroll
    for (int ni = 0; ni < 4; ni++)
      bb[ni] = *(const bf16x8*)&Bd[((0 + q) * 128 + wn + ni * 16 + li) * 8];
#pragma unroll
    for (int mi = 0; mi < 4; mi++)
#pragma unroll
      for (int ni = 0; ni < 4; ni++)
        acc[mi][ni] = MFMA16(af0[mi], bb[ni], acc[mi][ni]);
    {
      const int cb0 = (it < 11) ? (it + 1) * 8 : 88;  // clamp: keep addr valid
#pragma unroll
      for (int mi = 0; mi < 4; mi++)
        af0[mi] = *(const bf16x8*)(ap[mi] + (size_t)(cb0 + q) * 4096);
    }
    // ---- ks = 1: consume af1, prefetch af1 <- step 2*(it+1)+1
#pragma unroll
    for (int ni = 0; ni < 4; ni++)
      bb[ni] = *(const bf16x8*)&Bd[((4 + q) * 128 + wn + ni * 16 + li) * 8];
#pragma unroll
    for (int mi = 0; mi < 4; mi++)
#pragma unroll
      for (int ni = 0; ni < 4; ni++)
        acc[mi][ni] = MFMA16(af1[mi], bb[ni], acc[mi][ni]);
    {
      const int cb1 = (it < 11) ? (it + 1) * 8 + 4 : 92;
#pragma unroll
      for (int mi = 0; mi < 4; mi++)
        af1[mi] = *(const bf16x8*)(ap[mi] + (size_t)(cb1 + q) * 4096);
    }
    // retire this iteration's 4 stage loads (issued at top — ~full compute
    // phase of cover); keep the 8 af prefetches in flight across the barrier.
    asm volatile("s_waitcnt vmcnt(8)" ::: "memory");
    BAR();
  }

  // epilogue: E = acc + base + al + b1; relu; out += E @ W2 via MFMA.
  // All waves passed the final barrier; scratch in Bs[0] (per-wave regions).
  const int b = bc / CC, c = bc % CC;
  int fcol[4];
  float alb[4];
#pragma unroll
  for (int ni = 0; ni < 4; ni++) {
    int f = n0 + wn + ni * 16 + li;
    fcol[ni] = f;
    alb[ni] = al[(size_t)bc * H4 + f] + b1[f];
  }
  bf16x8 w2f[2];
#pragma unroll
  for (int ks = 0; ks < 2; ks++)
#pragma unroll
    for (int jj = 0; jj < 8; jj++) {
      int f = n0 + wn + ks * 32 + q * 8 + jj;
      float v = (li < 3) ? W2[(size_t)f * 3 + li] : 0.f;
      w2f[ks][jj] = (short)f2bf(v);
    }
  unsigned short* Ew = (unsigned short*)((char*)&Bs[0][0] + wave * 2304);

#pragma unroll
  for (int mi = 0; mi < 4; mi++) {
    float bs[4][4];
#pragma unroll
    for (int rr = 0; rr < 4; rr++) {
      int s_l = m0 + wm + mi * 16 + q * 4 + rr;
      const float* bp = base + (size_t)(b * SS + s_l) * H4;
#pragma unroll
      for (int ni = 0; ni < 4; ni++) bs[ni][rr] = bp[fcol[ni]];
    }
#pragma unroll
    for (int rr = 0; rr < 4; rr++)
#pragma unroll
      for (int ni = 0; ni < 4; ni++) {
        float v = acc[mi][ni][rr] + bs[ni][rr] + alb[ni];
        v = fmaxf(v, 0.f);
        Ew[(q * 4 + rr) * 72 + ni * 16 + li] = f2bf(v);
      }
    f32x4 oc = (f32x4){0.f, 0.f, 0.f, 0.f};
#pragma unroll
    for (int ks = 0; ks < 2; ks++) {
      bf16x8 ef = *(const bf16x8*)&Ew[li * 72 + ks * 32 + q * 8];
      oc = MFMA16(ef, w2f[ks], oc);
    }
#pragma unroll
    for (int rr = 0; rr < 4; rr++) {
      int s_l = m0 + wm + mi * 16 + q * 4 + rr;
      if (li < 3)
        atomicAdd(&out[((size_t)(b * SS + s_l) * CC + c) * 3 + li], oc[rr]);
    }
  }
}

// ---------------- host launch ----------------

extern "C" void kernel_launch(void* const* d_in, const int* in_sizes, int n_in,
                              void* d_out, int out_size, void* d_ws, size_t ws_size,
                              hipStream_t stream) {
  (void)in_sizes; (void)n_in; (void)ws_size; (void)out_size;
  const float* token = (const float*)d_in[0];
  const float* label = (const float*)d_in[1];
  const float* Wt    = (const float*)d_in[2];
  const float* bt    = (const float*)d_in[3];
  const float* Wl    = (const float*)d_in[4];
  const float* bl    = (const float*)d_in[5];
  const float* W1    = (const float*)d_in[6];
  const float* b1    = (const float*)d_in[7];
  const float* W2    = (const float*)d_in[8];
  const float* b2    = (const float*)d_in[9];
  float* out = (float*)d_out;

  char* p = (char*)d_ws;
  auto alloc = [&](size_t bytes) {
    char* r = p;
    p += (bytes + 255) & ~(size_t)255;
    return r;
  };
  unsigned short* TC  = (unsigned short*)alloc((size_t)96 * 1024 * 8 * 2);
  unsigned short* LC  = (unsigned short*)alloc((size_t)96 * 64 * 8 * 2);
  unsigned short* WtC = (unsigned short*)alloc((size_t)96 * 1536 * 8 * 2);
  unsigned short* WlC = (unsigned short*)alloc((size_t)96 * 1536 * 8 * 2);
  unsigned short* W1C = (unsigned short*)alloc((size_t)288 * 3072 * 8 * 2);
  unsigned short* TP  = (unsigned short*)alloc((size_t)192 * 1024 * 8 * 2);
  unsigned short* LP  = (unsigned short*)alloc((size_t)192 * 64 * 8 * 2);
  unsigned short* XC  = (unsigned short*)alloc((size_t)CC * BB * XC_STRIDE * 2);
  float* base = (float*)alloc((size_t)BB * SS * H4 * 4);
  float* al   = (float*)alloc((size_t)BB * CC * H4 * 4);

  // K1: small casts (TC/LC/WtC/WlC) + out init
  k_prep<<<1860, 256, 0, stream>>>(token, label, b2, Wt, Wl,
                                   TC, LC, out, WtC, WlC);
  // K2: G1+G2 fused projections + W1 cast riding the idle CUs
  k_mm1<<<3564, 256, 0, stream>>>(TC, LC, WtC, WlC, bt, bl, W1, TP, LP, W1C);
  // K3: G3+G4 GEMMs + make_x
  k_mm2<<<9816, 256, 0, stream>>>(TP, LP, W1C, base, al, XC);
  // K4: G5 scorer (R6 structure)
  k_scorer<<<dim3(24, 200), 256, 0, stream>>>(
      XC, W1C + (size_t)192 * H4 * 8, base, al, b1, W2, out);
}